// Round 10
// baseline (46.046 us; speedup 1.0000x reference)
//
#include <hip/hip_runtime.h>
#include <stdint.h>

#define N_DET    4096
#define HALF     2048
#define MAX_DET  100
#define NTHREADS 1024
#define DEC_THREADS 256
#define DEC_CHUNKS  16       // blocks per batch in decode kernel
#define IOU_THR  0.5f

typedef unsigned long long u64;

// Explicit-rounding helpers: prevent -ffp-contract=fast from FMA-fusing and
// changing bits vs the JAX/NumPy reference (R1-R9 all passed with absmax 0.0).
__device__ __forceinline__ float fadd(float a, float b) { return __fadd_rn(a, b); }
__device__ __forceinline__ float fsub(float a, float b) { return __fsub_rn(a, b); }
__device__ __forceinline__ float fmul(float a, float b) { return __fmul_rn(a, b); }

struct Box { float x1, y1, x2, y2; };

__device__ __forceinline__ Box decode_box(const float* __restrict__ box_b,
                                          const int*   __restrict__ idx_b,
                                          const float* __restrict__ anchors,
                                          int i, float sz0, float sz1)
{
    int ai = idx_b[i];
    float a0 = anchors[ai * 4 + 0];
    float a1 = anchors[ai * 4 + 1];
    float a2 = anchors[ai * 4 + 2];
    float a3 = anchors[ai * 4 + 3];
    float yc_a = fmul(fadd(a0, a2), 0.5f);
    float xc_a = fmul(fadd(a1, a3), 0.5f);
    float ha = fsub(a2, a0);
    float wa = fsub(a3, a1);
    float ty = box_b[i * 4 + 0];
    float tx = box_b[i * 4 + 1];
    float th = box_b[i * 4 + 2];
    float tw = box_b[i * 4 + 3];
    float we = fmul(expf(tw), wa);
    float he = fmul(expf(th), ha);
    float yc = fadd(fmul(ty, ha), yc_a);
    float xc = fadd(fmul(tx, wa), xc_a);
    Box r;
    r.x1 = fsub(xc, fmul(we, 0.5f));
    r.y1 = fsub(yc, fmul(he, 0.5f));
    r.x2 = fadd(xc, fmul(we, 0.5f));
    r.y2 = fadd(yc, fmul(he, 0.5f));
    r.x1 = fminf(fmaxf(r.x1, 0.f), sz0);
    r.y1 = fminf(fmaxf(r.y1, 0.f), sz1);
    r.x2 = fminf(fmaxf(r.x2, 0.f), sz0);
    r.y2 = fminf(fmaxf(r.y2, 0.f), sz1);
    return r;
}

__device__ __forceinline__ float sigmoidf_ref(float x)
{
    return __fdiv_rn(1.0f, __fadd_rn(1.0f, expf(-x)));
}

// head (earlier-selected) first: union = area[head] + area[cand] - inter
__device__ __forceinline__ bool iou_suppress(float hx1, float hy1, float hx2, float hy2, float har,
                                             float cx1, float cy1, float cx2, float cy2, float car)
{
    float lt0 = fmaxf(hx1, cx1);
    float lt1 = fmaxf(hy1, cy1);
    float rb0 = fminf(hx2, cx2);
    float rb1 = fminf(hy2, cy2);
    float w0 = fmaxf(fsub(rb0, lt0), 0.f);
    float w1 = fmaxf(fsub(rb1, lt1), 0.f);
    float inter = fmul(w0, w1);
    float uni = fsub(fadd(har, car), inter);
    float iou = __fdiv_rn(inter, fmaxf(uni, 1e-8f));
    return iou > IOU_THR;
}

// ---- bitonic helpers (register / shuffle) ----
__device__ __forceinline__ u64 shfl_xor_u64(u64 x, int mask)
{
    unsigned lo = (unsigned)x, hi = (unsigned)(x >> 32);
    lo = __shfl_xor(lo, mask, 64);
    hi = __shfl_xor(hi, mask, 64);
    return ((u64)hi << 32) | lo;
}

__device__ __forceinline__ void cex(u64& a, u64& b, bool desc)
{
    bool sw = desc ? (a < b) : (a > b);
    u64 ta = a, tb = b;
    a = sw ? tb : ta;
    b = sw ? ta : tb;
}

__device__ __forceinline__ void shuf_pass(u64 e[4], int d, bool desc, int l)
{
    bool lower = ((l & d) == 0);
    bool keepmax = (desc == lower);
    #pragma unroll
    for (int s = 0; s < 4; ++s) {
        u64 p = shfl_xor_u64(e[s], d);
        u64 mx = (e[s] > p) ? e[s] : p;
        u64 mn = (e[s] < p) ? e[s] : p;
        e[s] = keepmax ? mx : mn;
    }
}

// 2-slot descending merge step: element idx = 2*lane + slot, partner lane = l ^ d.
__device__ __forceinline__ void shuf_pass2(u64 e[2], int d, int l)
{
    bool keepmax = ((l & d) == 0);
    #pragma unroll
    for (int s = 0; s < 2; ++s) {
        u64 p = shfl_xor_u64(e[s], d);
        u64 mx = (e[s] > p) ? e[s] : p;
        u64 mn = (e[s] < p) ? e[s] : p;
        e[s] = keepmax ? mx : mn;
    }
}

// =====================  Kernel 1: wide-grid decode (validated R6-R9)  =====================
__global__ __launch_bounds__(DEC_THREADS)
void decode_kernel(const float* __restrict__ cls_outputs,
                   const float* __restrict__ box_outputs,
                   const int*   __restrict__ indices,
                   const float* __restrict__ anchors,
                   const float* __restrict__ img_scale,
                   const float* __restrict__ img_size,
                   float*       __restrict__ wmax,    // B * DEC_CHUNKS
                   u64*         __restrict__ wkeys,   // B * N_DET
                   float4*      __restrict__ wboxes)  // B * N_DET
{
    const int blk   = blockIdx.x;
    const int b     = blk / DEC_CHUNKS;
    const int chunk = blk % DEC_CHUNKS;
    const int i     = chunk * DEC_THREADS + threadIdx.x;

    const float* cls_b = cls_outputs + (size_t)b * N_DET;
    const float* box_b = box_outputs + (size_t)b * N_DET * 4;
    const int*   idx_b = indices + (size_t)b * N_DET;
    const float  scale = img_scale[b];
    const float  sz0   = __fdiv_rn(img_size[b * 2 + 0], scale);
    const float  sz1   = __fdiv_rn(img_size[b * 2 + 1], scale);

    Box r = decode_box(box_b, idx_b, anchors, i, sz0, sz1);
    float sc = sigmoidf_ref(cls_b[i]);

    wboxes[(size_t)b * N_DET + i] = make_float4(r.x1, r.y1, r.x2, r.y2);
    wkeys[(size_t)b * N_DET + i] =
        ((u64)__float_as_uint(sc) << 32) | (unsigned)(N_DET - 1 - i);

    float lmax = fmaxf(fmaxf(r.x1, r.y1), fmaxf(r.x2, r.y2));
    for (int o = 32; o; o >>= 1) lmax = fmaxf(lmax, __shfl_xor(lmax, o, 64));
    __shared__ float wred[DEC_THREADS / 64];
    if ((threadIdx.x & 63) == 0) wred[threadIdx.x >> 6] = lmax;
    __syncthreads();
    if (threadIdx.x == 0) {
        float m = wred[0];
        #pragma unroll
        for (int k = 1; k < DEC_THREADS / 64; ++k) m = fmaxf(m, wred[k]);
        wmax[b * DEC_CHUNKS + chunk] = m;   // plain store: overwritten every replay
    }
}

// =====================  Kernel 2: fused in-LDS half-sorts + pre-merge + scan + emit  ==========
// Waves 0-7 sort half A (orig 0..2047), waves 8-15 sort half B (orig 2048..4095),
// both descending, entirely in LDS; then the validated pre-merge + scan run on the result.
__global__ __launch_bounds__(NTHREADS, 1)
void scan_kernel(const int*    __restrict__ classes,    // B,N
                 const float*  __restrict__ img_scale,  // B
                 const float*  __restrict__ wmax,
                 const u64*    __restrict__ wkeys,      // unsorted keys
                 const float4* __restrict__ wboxes,
                 float*        __restrict__ out)        // B,MAX_DET,6
{
    __shared__ u64    keys[N_DET];     // 32 KB: [0:2048) half A desc, [2048:4096) half B desc
    __shared__ u64    mstream[1024];   // merged A[0:512] ∪ B[0:512]; [0:512] = exact top-512
    __shared__ int    waveA[8];
    __shared__ float4 bbox[64];
    __shared__ float  barr[64];
    __shared__ int    borig[64];
    __shared__ u64    bkey[64];
    __shared__ u64    extp[16];
    __shared__ unsigned Cplo[16][64];
    __shared__ unsigned Cphi[16][64];
    __shared__ int    sel[MAX_DET];
    __shared__ float  selsc[MAX_DET];
    __shared__ float4 hbox4[MAX_DET];
    __shared__ float  harr[MAX_DET];
    __shared__ int    sh_count;

    const int b  = blockIdx.x;
    const int t  = threadIdx.x;
    const int l  = t & 63;             // lane
    const int th = t & 511;            // thread-in-half
    const int hoff = (t >> 9) * HALF;  // half base (0 or 2048)

    const int*    cls_id_b = classes + (size_t)b * N_DET;
    const float   scale    = img_scale[b];
    const u64*    wk = wkeys + (size_t)b * N_DET;
    const float4* wb = wboxes + (size_t)b * N_DET;

    float mm = wmax[b * DEC_CHUNKS + 0];
    #pragma unroll
    for (int k = 1; k < DEC_CHUNKS; ++k) mm = fmaxf(mm, wmax[b * DEC_CHUNKS + k]);
    const float M = fadd(mm, 1.0f);   // jnp.max(b) + 1.0

    // ---------- In-LDS half-sorts (validated network, t -> th per half) ----------
    // Thread t owns global elements 4t..4t+3 == hoff + 4*th + s (blocked, half-contained).
    u64 e[4];
    #pragma unroll
    for (int s = 0; s < 4; ++s) e[s] = wk[4 * t + s];

    // Phase A: wave-local bitonic, k=2..256; local il = 4*th+s, desc <=> (il & k)==0
    cex(e[0], e[1], true);
    cex(e[2], e[3], false);
    for (int k = 4; k <= 128; k <<= 1) {
        bool desc = (l & (k >> 2)) == 0;
        for (int j = k >> 1; j >= 4; j >>= 1) shuf_pass(e, j >> 2, desc, l);
        cex(e[0], e[2], desc); cex(e[1], e[3], desc);
        cex(e[0], e[1], desc); cex(e[2], e[3], desc);
    }
    {   // k = 256: wave-parity-in-half direction
        bool desc = ((th >> 6) & 1) == 0;
        for (int j = 128; j >= 4; j >>= 1) shuf_pass(e, j >> 2, desc, l);
        cex(e[0], e[2], desc); cex(e[1], e[3], desc);
        cex(e[0], e[1], desc); cex(e[2], e[3], desc);
    }
    #pragma unroll
    for (int s = 0; s < 4; ++s) keys[4 * t + s] = e[s];

    // Phase B: cross-wave merges k = 512..2048, per half (local indices + hoff)
    for (int k = 512; k <= HALF; k <<= 1) {
        for (int j = k >> 1; j >= 256; j >>= 1) {
            __syncthreads();
            #pragma unroll
            for (int vv = 0; vv < 2; ++vv) {
                int v = th + vv * 512;                 // 0..1023 pairs within half
                int i   = ((v & ~(j - 1)) << 1) | (v & (j - 1));
                int ixj = i | j;
                bool desc = ((i & k) == 0);
                u64 a = keys[hoff + i], c = keys[hoff + ixj];
                bool sw = desc ? (a < c) : (a > c);
                if (sw) { keys[hoff + i] = c; keys[hoff + ixj] = a; }
            }
        }
        __syncthreads();
        u64 f[4];
        #pragma unroll
        for (int s = 0; s < 4; ++s) f[s] = keys[4 * t + s];
        bool desc = (th & (k >> 2)) == 0;              // (4*th & k)==0; k=2048 -> true (both halves desc)
        for (int j = 128; j >= 4; j >>= 1) shuf_pass(f, j >> 2, desc, l);
        cex(f[0], f[2], desc); cex(f[1], f[3], desc);
        cex(f[0], f[1], desc); cex(f[2], f[3], desc);
        #pragma unroll
        for (int s = 0; s < 4; ++s) keys[4 * t + s] = f[s];
    }
    // scan-state init folded into the final sort barrier
    if (t < MAX_DET) sel[t] = -1;
    if (t == 0) sh_count = 0;
    __syncthreads();   // sorted halves + init visible

    // ---------- Pre-merge: mstream = A[0:512] desc ++ B[0:512] asc (bitonic) ----------
    if (t < 512) mstream[t] = keys[t];
    else         mstream[t] = keys[HALF + 511 - (t - 512)];
    __syncthreads();
    {   // j = 512
        if (t < 512) {
            u64 a = mstream[t], c = mstream[t + 512];
            if (a < c) { mstream[t] = c; mstream[t + 512] = a; }
        }
        __syncthreads();
        // j = 256
        if (t < 512) {
            int i   = ((t & ~255) << 1) | (t & 255);
            int ixj = i | 256;
            u64 a = mstream[i], c = mstream[ixj];
            if (a < c) { mstream[i] = c; mstream[ixj] = a; }
        }
        __syncthreads();
        // j = 128..1 : blocked register phase (validated, desc = true)
        if (t < 256) {
            u64 f[4];
            #pragma unroll
            for (int s = 0; s < 4; ++s) f[s] = mstream[4 * t + s];
            for (int j = 128; j >= 4; j >>= 1) shuf_pass(f, j >> 2, true, l);
            cex(f[0], f[2], true); cex(f[1], f[3], true);
            cex(f[0], f[1], true); cex(f[2], f[3], true);
            #pragma unroll
            for (int s = 0; s < 4; ++s) mstream[4 * t + s] = f[s];
        }
        __syncthreads();
    }

    // count A-side elements in the top-512 (exact resume pointers for fallback)
    {
        bool isA = false;
        if (t < 512) {
            int orig = N_DET - 1 - (int)(unsigned)(mstream[t] & 0xFFFFFFFFull);
            isA = (orig < HALF);
        }
        u64 bal = __ballot(isA ? 1 : 0);
        if ((t & 63) == 0 && (t >> 6) < 8) waveA[t >> 6] = __popcll(bal);
        __syncthreads();
    }
    int pa = 0;
    #pragma unroll
    for (int w = 0; w < 8; ++w) pa += waveA[w];
    int pb = 512 - pa;                 // fallback resume pointers (uniform)

    const int j = t & 63;
    const int g = t >> 6;

    for (int c = 0; c < N_DET; c += 64) {
        int count = sh_count;          // uniform after barrier
        if (count >= MAX_DET) break;

        if (c + 64 <= 512) {
            // ---- 1-fast. publish from pre-merged stream ----
            if (t < 64) {
                u64 key = mstream[c + t];
                int orig = N_DET - 1 - (int)(unsigned)(key & 0xFFFFFFFFull);
                bkey[t] = key; borig[t] = orig;
                float4 bb = wb[orig];
                float off = fmul((float)cls_id_b[orig], M);  // c.astype(f32)*(max+1)
                float x1 = fadd(bb.x, off), y1 = fadd(bb.y, off);
                float x2 = fadd(bb.z, off), y2 = fadd(bb.w, off);
                bbox[t] = make_float4(x1, y1, x2, y2);
                barr[t] = fmul(fmaxf(fsub(x2, x1), 0.f), fmaxf(fsub(y2, y1), 0.f));
            }
        } else {
            // ---- 1-slow. fallback: windowed 2-way merge from LDS halves (validated R8/R9) ----
            if (t < 64) {
                u64 ee[2];
                if (l < 32) {
                    int p0 = pa + 2 * l;
                    ee[0] = (p0     < HALF) ? keys[p0]     : 0ull;
                    ee[1] = (p0 + 1 < HALF) ? keys[p0 + 1] : 0ull;
                } else {
                    int p  = 2 * (l - 32);
                    int q0 = pb + 63 - p;
                    ee[0] = (q0     < HALF) ? keys[HALF + q0]     : 0ull;
                    ee[1] = (q0 - 1 < HALF && q0 - 1 >= 0) ? keys[HALF + q0 - 1] : 0ull;
                }
                shuf_pass2(ee, 32, l); shuf_pass2(ee, 16, l); shuf_pass2(ee, 8, l);
                shuf_pass2(ee, 4, l);  shuf_pass2(ee, 2, l);  shuf_pass2(ee, 1, l);
                cex(ee[0], ee[1], true);

                int orig0 = N_DET - 1 - (int)(unsigned)(ee[0] & 0xFFFFFFFFull);
                int orig1 = N_DET - 1 - (int)(unsigned)(ee[1] & 0xFFFFFFFFull);
                bool r0 = (l < 32) && (ee[0] != 0ull);
                bool r1 = (l < 32) && (ee[1] != 0ull);
                if (l < 32) {
                    #pragma unroll
                    for (int s = 0; s < 2; ++s) {
                        int  r    = 2 * l + s;
                        u64  key  = s ? ee[1] : ee[0];
                        int  orig = s ? orig1 : orig0;
                        bool ok   = s ? r1 : r0;
                        bkey[r] = key;
                        if (ok) {
                            float4 bb = wb[orig];
                            float off = fmul((float)cls_id_b[orig], M);
                            float x1 = fadd(bb.x, off), y1 = fadd(bb.y, off);
                            float x2 = fadd(bb.z, off), y2 = fadd(bb.w, off);
                            bbox[r] = make_float4(x1, y1, x2, y2);
                            barr[r] = fmul(fmaxf(fsub(x2, x1), 0.f), fmaxf(fsub(y2, y1), 0.f));
                            borig[r] = orig;
                        } else {
                            bbox[r] = make_float4(0.f, 0.f, 0.f, 0.f);
                            barr[r] = 0.f;
                            borig[r] = -1;
                        }
                    }
                }
                u64 bR0 = __ballot(r0), bR1 = __ballot(r1);
                u64 bA0 = __ballot(r0 && (orig0 < HALF));
                u64 bA1 = __ballot(r1 && (orig1 < HALF));
                int real = __popcll(bR0) + __popcll(bR1);
                int aw   = __popcll(bA0) + __popcll(bA1);
                pa += aw;
                pb += real - aw;
            }
        }
        __syncthreads();

        // ---- 2. all 16 waves: suppression partials (validated R7-R9) ----
        float4 c4  = bbox[j];
        float  car = barr[j];
        const bool valid = (borig[j] >= 0);

        bool sup = !valid;
        for (int k = g; k < count; k += 16) {
            float4 h4 = hbox4[k];
            sup = sup | iou_suppress(h4.x, h4.y, h4.z, h4.w, harr[k],
                                     c4.x, c4.y, c4.z, c4.w, car);
        }
        u64 bal = __ballot(sup ? 1 : 0);
        if ((t & 63) == 0) extp[g] = bal;

        unsigned cplo = 0, cphi = 0;
        for (int r = g + 1; r < 64; r += 16) {
            int q = j ^ r;
            float4 q4 = bbox[q];
            float qar = barr[q];
            bool hit = (q > j) & valid & (borig[q] >= 0) &
                       iou_suppress(c4.x, c4.y, c4.z, c4.w, car,
                                    q4.x, q4.y, q4.z, q4.w, qar);
            unsigned bit = hit ? 1u : 0u;
            if (q < 32) cplo |= bit << q; else cphi |= bit << (q - 32);
        }
        Cplo[g][j] = cplo;
        Cphi[g][j] = cphi;
        __syncthreads();

        // ---- 3. wave 0: combine partials, exact greedy closure, append heads ----
        if (t < 64) {
            const int lane = t;
            u64 ext = 0;
            #pragma unroll
            for (int gg = 0; gg < 16; ++gg) ext |= extp[gg];
            unsigned lo = 0, hi = 0;
            #pragma unroll
            for (int gg = 0; gg < 16; ++gg) { lo |= Cplo[gg][lane]; hi |= Cphi[gg][lane]; }
            u64 C = ((u64)hi << 32) | lo;
            u64 hasC = __ballot(C != 0ull);

            u64 alive = ~ext;
            u64 selmask = 0;
            int total = count;
            while (alive && total < MAX_DET) {
                int k = __ffsll(alive) - 1;
                selmask |= (1ull << k);
                alive &= ~(1ull << k);
                ++total;
                if ((hasC >> k) & 1ull) {
                    unsigned clo = __shfl((int)(unsigned)C, k, 64);
                    unsigned chi = __shfl((int)(unsigned)(C >> 32), k, 64);
                    alive &= ~(((u64)chi << 32) | clo);
                }
            }

            if ((selmask >> lane) & 1ull) {
                int p = count + __popcll(selmask & ((1ull << lane) - 1ull));
                hbox4[p] = bbox[lane];
                harr[p]  = barr[lane];
                sel[p]   = borig[lane];
                selsc[p] = __uint_as_float((unsigned)(bkey[lane] >> 32));  // exact sigmoid bits
            }
            if (lane == 0) sh_count = total;
        }
        __syncthreads();
    }

    // ---------- Emit (wave 0; validated path) ----------
    if (t >= 64) return;
    for (int r = t; r < MAX_DET; r += 64) {
        int sidx = sel[r];
        float* o = out + (size_t)b * MAX_DET * 6 + (size_t)r * 6;
        if (sidx < 0) {
            o[0] = 0.f; o[1] = 0.f; o[2] = 0.f; o[3] = 0.f; o[4] = 0.f; o[5] = 0.f;
        } else {
            float4 bb = wb[sidx];
            int c = cls_id_b[sidx];
            o[0] = fmul(bb.x, scale);
            o[1] = fmul(bb.y, scale);
            o[2] = fmul(bb.z, scale);
            o[3] = fmul(bb.w, scale);
            o[4] = selsc[r];
            o[5] = (float)(c + 1);
        }
    }
}

extern "C" void kernel_launch(void* const* d_in, const int* in_sizes, int n_in,
                              void* d_out, int out_size, void* d_ws, size_t ws_size,
                              hipStream_t stream)
{
    const float* cls_outputs = (const float*)d_in[0];
    const float* box_outputs = (const float*)d_in[1];
    const int*   indices     = (const int*)d_in[2];
    const int*   classes     = (const int*)d_in[3];
    const float* anchors     = (const float*)d_in[4];
    const float* img_scale   = (const float*)d_in[5];
    const float* img_size    = (const float*)d_in[6];
    float*       out         = (float*)d_out;

    const int B = in_sizes[5];   // img_scale has B elements

    // workspace layout: [wmax: B*16 floats][pad to 1KB][wkeys: B*4096 u64][wboxes: B*4096 float4]
    char* wsb = (char*)d_ws;
    float*  wmax   = (float*)wsb;
    u64*    wkeys  = (u64*)(wsb + 1024);
    float4* wboxes = (float4*)(wsb + 1024 + (size_t)B * N_DET * sizeof(u64));

    decode_kernel<<<dim3(B * DEC_CHUNKS), dim3(DEC_THREADS), 0, stream>>>(
        cls_outputs, box_outputs, indices, anchors, img_scale, img_size,
        wmax, wkeys, wboxes);

    scan_kernel<<<dim3(B), dim3(NTHREADS), 0, stream>>>(
        classes, img_scale, wmax, wkeys, wboxes, out);
}

// Round 11
// 37.465 us; speedup vs baseline: 1.2290x; 1.2290x over previous
//
#include <hip/hip_runtime.h>
#include <stdint.h>

#define N_DET    4096
#define HALF     2048
#define MAX_DET  100
#define NTHREADS 1024
#define SORT_THREADS 512
#define IOU_THR  0.5f

typedef unsigned long long u64;

// Explicit-rounding helpers: prevent -ffp-contract=fast from FMA-fusing and
// changing bits vs the JAX/NumPy reference (R1-R10 all passed with absmax 0.0).
__device__ __forceinline__ float fadd(float a, float b) { return __fadd_rn(a, b); }
__device__ __forceinline__ float fsub(float a, float b) { return __fsub_rn(a, b); }
__device__ __forceinline__ float fmul(float a, float b) { return __fmul_rn(a, b); }

struct Box { float x1, y1, x2, y2; };

__device__ __forceinline__ Box decode_box_v(const float4 bo, const float4 a,
                                            float sz0, float sz1)
{
    float yc_a = fmul(fadd(a.x, a.z), 0.5f);
    float xc_a = fmul(fadd(a.y, a.w), 0.5f);
    float ha = fsub(a.z, a.x);
    float wa = fsub(a.w, a.y);
    float ty = bo.x, tx = bo.y, th = bo.z, tw = bo.w;
    float we = fmul(expf(tw), wa);
    float he = fmul(expf(th), ha);
    float yc = fadd(fmul(ty, ha), yc_a);
    float xc = fadd(fmul(tx, wa), xc_a);
    Box r;
    r.x1 = fsub(xc, fmul(we, 0.5f));
    r.y1 = fsub(yc, fmul(he, 0.5f));
    r.x2 = fadd(xc, fmul(we, 0.5f));
    r.y2 = fadd(yc, fmul(he, 0.5f));
    r.x1 = fminf(fmaxf(r.x1, 0.f), sz0);
    r.y1 = fminf(fmaxf(r.y1, 0.f), sz1);
    r.x2 = fminf(fmaxf(r.x2, 0.f), sz0);
    r.y2 = fminf(fmaxf(r.y2, 0.f), sz1);
    return r;
}

__device__ __forceinline__ float sigmoidf_ref(float x)
{
    return __fdiv_rn(1.0f, __fadd_rn(1.0f, expf(-x)));
}

// head (earlier-selected) first: union = area[head] + area[cand] - inter
__device__ __forceinline__ bool iou_suppress(float hx1, float hy1, float hx2, float hy2, float har,
                                             float cx1, float cy1, float cx2, float cy2, float car)
{
    float lt0 = fmaxf(hx1, cx1);
    float lt1 = fmaxf(hy1, cy1);
    float rb0 = fminf(hx2, cx2);
    float rb1 = fminf(hy2, cy2);
    float w0 = fmaxf(fsub(rb0, lt0), 0.f);
    float w1 = fmaxf(fsub(rb1, lt1), 0.f);
    float inter = fmul(w0, w1);
    float uni = fsub(fadd(har, car), inter);
    float iou = __fdiv_rn(inter, fmaxf(uni, 1e-8f));
    return iou > IOU_THR;
}

// ---- bitonic helpers (register / shuffle) ----
__device__ __forceinline__ u64 shfl_xor_u64(u64 x, int mask)
{
    unsigned lo = (unsigned)x, hi = (unsigned)(x >> 32);
    lo = __shfl_xor(lo, mask, 64);
    hi = __shfl_xor(hi, mask, 64);
    return ((u64)hi << 32) | lo;
}

__device__ __forceinline__ void cex(u64& a, u64& b, bool desc)
{
    bool sw = desc ? (a < b) : (a > b);
    u64 ta = a, tb = b;
    a = sw ? tb : ta;
    b = sw ? ta : tb;
}

__device__ __forceinline__ void shuf_pass(u64 e[4], int d, bool desc, int l)
{
    bool lower = ((l & d) == 0);
    bool keepmax = (desc == lower);
    #pragma unroll
    for (int s = 0; s < 4; ++s) {
        u64 p = shfl_xor_u64(e[s], d);
        u64 mx = (e[s] > p) ? e[s] : p;
        u64 mn = (e[s] < p) ? e[s] : p;
        e[s] = keepmax ? mx : mn;
    }
}

// 2-slot descending merge step: element idx = 2*lane + slot, partner lane = l ^ d.
__device__ __forceinline__ void shuf_pass2(u64 e[2], int d, int l)
{
    bool keepmax = ((l & d) == 0);
    #pragma unroll
    for (int s = 0; s < 2; ++s) {
        u64 p = shfl_xor_u64(e[s], d);
        u64 mx = (e[s] > p) ? e[s] : p;
        u64 mn = (e[s] < p) ? e[s] : p;
        e[s] = keepmax ? mx : mn;
    }
}

// ============  Kernel 1: fused decode + half-sort (R9 sort geometry preserved)  ============
// grid = B*2 blocks x 512 threads; block handles 2048 boxes: decode (4/thread, blocked),
// keys in registers -> validated half-sort in LDS -> sorted keys to global.
__global__ __launch_bounds__(SORT_THREADS, 1)
void dec_sort_kernel(const float* __restrict__ cls_outputs,
                     const float* __restrict__ box_outputs,
                     const int*   __restrict__ indices,
                     const float* __restrict__ anchors,
                     const float* __restrict__ img_scale,
                     const float* __restrict__ img_size,
                     float*       __restrict__ wmax,    // B * 2
                     u64*         __restrict__ wkeys,   // B * N_DET (sorted halves)
                     float4*      __restrict__ wboxes)  // B * N_DET (by orig index)
{
    __shared__ u64   keys[HALF];     // 16 KB
    __shared__ float wred[8];

    const int blk  = blockIdx.x;
    const int b    = blk >> 1;
    const int base = (blk & 1) * HALF;     // element offset within batch
    const int t    = threadIdx.x;
    const int l    = t & 63;

    const float* cls_b = cls_outputs + (size_t)b * N_DET;
    const float* box_b = box_outputs + (size_t)b * N_DET * 4;
    const int*   idx_b = indices + (size_t)b * N_DET;
    const float  scale = img_scale[b];
    const float  sz0   = __fdiv_rn(img_size[b * 2 + 0], scale);
    const float  sz1   = __fdiv_rn(img_size[b * 2 + 1], scale);

    // ---- decode 4 consecutive boxes/thread (identical arithmetic to R6-R10 decode) ----
    u64 e[4];
    float lmax = 0.0f;
    const int4   idx4 = ((const int4*)(idx_b + base))[t];
    const float4 cl4  = ((const float4*)(cls_b + base))[t];
    const int   idxs[4] = { idx4.x, idx4.y, idx4.z, idx4.w };
    const float cls4[4] = { cl4.x, cl4.y, cl4.z, cl4.w };
    #pragma unroll
    for (int s = 0; s < 4; ++s) {
        int i = base + 4 * t + s;              // global index within batch
        float4 bo = ((const float4*)box_b)[i];          // ty,tx,th,tw
        float4 an = ((const float4*)anchors)[idxs[s]];  // a0,a1,a2,a3
        Box r = decode_box_v(bo, an, sz0, sz1);
        wboxes[(size_t)b * N_DET + i] = make_float4(r.x1, r.y1, r.x2, r.y2);
        lmax = fmaxf(lmax, fmaxf(fmaxf(r.x1, r.y1), fmaxf(r.x2, r.y2)));
        float sc = sigmoidf_ref(cls4[s]);
        e[s] = ((u64)__float_as_uint(sc) << 32) | (unsigned)(N_DET - 1 - i);
    }
    for (int o = 32; o; o >>= 1) lmax = fmaxf(lmax, __shfl_xor(lmax, o, 64));
    if (l == 0) wred[t >> 6] = lmax;

    // ---- validated half-sort (R8/R9 network; th == t, 512 threads, 2048 elems) ----
    // Phase A: wave-local bitonic, k=2..256; il = 4t+s, desc <=> (il & k)==0
    cex(e[0], e[1], true);
    cex(e[2], e[3], false);
    for (int k = 4; k <= 128; k <<= 1) {
        bool desc = (l & (k >> 2)) == 0;
        for (int j = k >> 1; j >= 4; j >>= 1) shuf_pass(e, j >> 2, desc, l);
        cex(e[0], e[2], desc); cex(e[1], e[3], desc);
        cex(e[0], e[1], desc); cex(e[2], e[3], desc);
    }
    {   // k = 256: wave-parity direction
        bool desc = ((t >> 6) & 1) == 0;
        for (int j = 128; j >= 4; j >>= 1) shuf_pass(e, j >> 2, desc, l);
        cex(e[0], e[2], desc); cex(e[1], e[3], desc);
        cex(e[0], e[1], desc); cex(e[2], e[3], desc);
    }
    #pragma unroll
    for (int s = 0; s < 4; ++s) keys[4 * t + s] = e[s];

    // Phase B: cross-wave merges k = 512..2048
    for (int k = 512; k <= HALF; k <<= 1) {
        for (int j = k >> 1; j >= 256; j >>= 1) {
            __syncthreads();
            #pragma unroll
            for (int vv = 0; vv < 2; ++vv) {
                int v = t + vv * SORT_THREADS;          // 0..1023 pairs
                int i   = ((v & ~(j - 1)) << 1) | (v & (j - 1));
                int ixj = i | j;
                bool desc = ((i & k) == 0);
                u64 a = keys[i], c = keys[ixj];
                bool sw = desc ? (a < c) : (a > c);
                if (sw) { keys[i] = c; keys[ixj] = a; }
            }
        }
        __syncthreads();
        u64 f[4];
        #pragma unroll
        for (int s = 0; s < 4; ++s) f[s] = keys[4 * t + s];
        bool desc = (t & (k >> 2)) == 0;               // (4t&k)==0
        for (int j = 128; j >= 4; j >>= 1) shuf_pass(f, j >> 2, desc, l);
        cex(f[0], f[2], desc); cex(f[1], f[3], desc);
        cex(f[0], f[1], desc); cex(f[2], f[3], desc);
        #pragma unroll
        for (int s = 0; s < 4; ++s) keys[4 * t + s] = f[s];
    }
    __syncthreads();
    u64* gk = wkeys + (size_t)b * N_DET + base;
    #pragma unroll
    for (int s = 0; s < 4; ++s) gk[4 * t + s] = keys[4 * t + s];

    if (t == 0) {
        float m = wred[0];
        #pragma unroll
        for (int k = 1; k < 8; ++k) m = fmaxf(m, wred[k]);
        wmax[blk] = m;   // plain store: overwritten every replay
    }
}

// =====================  Kernel 2: pre-merged top-512 stream + scan (verbatim R9)  ==============
__global__ __launch_bounds__(NTHREADS, 1)
void scan_kernel(const int*    __restrict__ classes,    // B,N
                 const float*  __restrict__ img_scale,  // B
                 const float*  __restrict__ wmax,       // B * 2
                 const u64*    __restrict__ wkeys,      // sorted halves
                 const float4* __restrict__ wboxes,
                 float*        __restrict__ out)        // B,MAX_DET,6
{
    __shared__ u64    mstream[1024];   // merged A[0:512] ∪ B[0:512]; [0:512] = exact top-512
    __shared__ int    waveA[8];
    __shared__ float4 bbox[64];
    __shared__ float  barr[64];
    __shared__ int    borig[64];
    __shared__ u64    bkey[64];
    __shared__ u64    extp[16];
    __shared__ unsigned Cplo[16][64];
    __shared__ unsigned Cphi[16][64];
    __shared__ int    sel[MAX_DET];
    __shared__ float  selsc[MAX_DET];
    __shared__ float4 hbox4[MAX_DET];
    __shared__ float  harr[MAX_DET];
    __shared__ int    sh_count;

    const int b = blockIdx.x;
    const int t = threadIdx.x;
    const int l = t & 63;

    const int*    cls_id_b = classes + (size_t)b * N_DET;
    const float   scale    = img_scale[b];
    const u64*    gA = wkeys + (size_t)b * N_DET;    // half A: orig 0..2047, desc
    const u64*    gB = gA + HALF;                    // half B: orig 2048..4095, desc
    const float4* wb = wboxes + (size_t)b * N_DET;

    const float M = fadd(fmaxf(wmax[b * 2 + 0], wmax[b * 2 + 1]), 1.0f);  // jnp.max(b)+1.0

    // ---------- Pre-merge: mstream = A[0:512] desc ++ B[0:512] asc (bitonic) ----------
    if (t < 512) mstream[t] = gA[t];
    else         mstream[t] = gB[511 - (t - 512)];
    if (t < MAX_DET) sel[t] = -1;
    if (t == 0) sh_count = 0;
    __syncthreads();

    {   // j = 512
        if (t < 512) {
            u64 a = mstream[t], c = mstream[t + 512];
            if (a < c) { mstream[t] = c; mstream[t + 512] = a; }
        }
        __syncthreads();
        // j = 256
        if (t < 512) {
            int i   = ((t & ~255) << 1) | (t & 255);
            int ixj = i | 256;
            u64 a = mstream[i], c = mstream[ixj];
            if (a < c) { mstream[i] = c; mstream[ixj] = a; }
        }
        __syncthreads();
        // j = 128..1 : blocked register phase (validated, desc = true)
        if (t < 256) {
            u64 f[4];
            #pragma unroll
            for (int s = 0; s < 4; ++s) f[s] = mstream[4 * t + s];
            for (int j = 128; j >= 4; j >>= 1) shuf_pass(f, j >> 2, true, l);
            cex(f[0], f[2], true); cex(f[1], f[3], true);
            cex(f[0], f[1], true); cex(f[2], f[3], true);
            #pragma unroll
            for (int s = 0; s < 4; ++s) mstream[4 * t + s] = f[s];
        }
        __syncthreads();
    }

    // count A-side elements in the top-512 (exact resume pointers for fallback)
    {
        bool isA = false;
        if (t < 512) {
            int orig = N_DET - 1 - (int)(unsigned)(mstream[t] & 0xFFFFFFFFull);
            isA = (orig < HALF);
        }
        u64 bal = __ballot(isA ? 1 : 0);
        if ((t & 63) == 0 && (t >> 6) < 8) waveA[t >> 6] = __popcll(bal);
        __syncthreads();
    }
    int pa = 0;
    #pragma unroll
    for (int w = 0; w < 8; ++w) pa += waveA[w];
    int pb = 512 - pa;                 // fallback resume pointers (uniform)

    const int j = t & 63;
    const int g = t >> 6;

    for (int c = 0; c < N_DET; c += 64) {
        int count = sh_count;          // uniform after barrier
        if (count >= MAX_DET) break;

        if (c + 64 <= 512) {
            // ---- 1-fast. publish from pre-merged stream ----
            if (t < 64) {
                u64 key = mstream[c + t];
                int orig = N_DET - 1 - (int)(unsigned)(key & 0xFFFFFFFFull);
                bkey[t] = key; borig[t] = orig;
                float4 bb = wb[orig];
                float off = fmul((float)cls_id_b[orig], M);  // c.astype(f32)*(max+1)
                float x1 = fadd(bb.x, off), y1 = fadd(bb.y, off);
                float x2 = fadd(bb.z, off), y2 = fadd(bb.w, off);
                bbox[t] = make_float4(x1, y1, x2, y2);
                barr[t] = fmul(fmaxf(fsub(x2, x1), 0.f), fmaxf(fsub(y2, y1), 0.f));
            }
        } else {
            // ---- 1-slow. fallback: windowed 2-way merge (validated R8/R9; exact, rare) ----
            if (t < 64) {
                u64 ee[2];
                if (l < 32) {
                    int p0 = pa + 2 * l;
                    ee[0] = (p0     < HALF) ? gA[p0]     : 0ull;
                    ee[1] = (p0 + 1 < HALF) ? gA[p0 + 1] : 0ull;
                } else {
                    int p  = 2 * (l - 32);
                    int q0 = pb + 63 - p;
                    ee[0] = (q0     < HALF) ? gB[q0]     : 0ull;
                    ee[1] = (q0 - 1 < HALF && q0 - 1 >= 0) ? gB[q0 - 1] : 0ull;
                }
                shuf_pass2(ee, 32, l); shuf_pass2(ee, 16, l); shuf_pass2(ee, 8, l);
                shuf_pass2(ee, 4, l);  shuf_pass2(ee, 2, l);  shuf_pass2(ee, 1, l);
                cex(ee[0], ee[1], true);

                int orig0 = N_DET - 1 - (int)(unsigned)(ee[0] & 0xFFFFFFFFull);
                int orig1 = N_DET - 1 - (int)(unsigned)(ee[1] & 0xFFFFFFFFull);
                bool r0 = (l < 32) && (ee[0] != 0ull);
                bool r1 = (l < 32) && (ee[1] != 0ull);
                if (l < 32) {
                    #pragma unroll
                    for (int s = 0; s < 2; ++s) {
                        int  r    = 2 * l + s;
                        u64  key  = s ? ee[1] : ee[0];
                        int  orig = s ? orig1 : orig0;
                        bool ok   = s ? r1 : r0;
                        bkey[r] = key;
                        if (ok) {
                            float4 bb = wb[orig];
                            float off = fmul((float)cls_id_b[orig], M);
                            float x1 = fadd(bb.x, off), y1 = fadd(bb.y, off);
                            float x2 = fadd(bb.z, off), y2 = fadd(bb.w, off);
                            bbox[r] = make_float4(x1, y1, x2, y2);
                            barr[r] = fmul(fmaxf(fsub(x2, x1), 0.f), fmaxf(fsub(y2, y1), 0.f));
                            borig[r] = orig;
                        } else {
                            bbox[r] = make_float4(0.f, 0.f, 0.f, 0.f);
                            barr[r] = 0.f;
                            borig[r] = -1;
                        }
                    }
                }
                u64 bR0 = __ballot(r0), bR1 = __ballot(r1);
                u64 bA0 = __ballot(r0 && (orig0 < HALF));
                u64 bA1 = __ballot(r1 && (orig1 < HALF));
                int real = __popcll(bR0) + __popcll(bR1);
                int aw   = __popcll(bA0) + __popcll(bA1);
                pa += aw;
                pb += real - aw;
            }
        }
        __syncthreads();

        // ---- 2. all 16 waves: suppression partials (validated R7-R10) ----
        float4 c4  = bbox[j];
        float  car = barr[j];
        const bool valid = (borig[j] >= 0);

        bool sup = !valid;
        for (int k = g; k < count; k += 16) {
            float4 h4 = hbox4[k];
            sup = sup | iou_suppress(h4.x, h4.y, h4.z, h4.w, harr[k],
                                     c4.x, c4.y, c4.z, c4.w, car);
        }
        u64 bal = __ballot(sup ? 1 : 0);
        if ((t & 63) == 0) extp[g] = bal;

        unsigned cplo = 0, cphi = 0;
        for (int r = g + 1; r < 64; r += 16) {
            int q = j ^ r;
            float4 q4 = bbox[q];
            float qar = barr[q];
            bool hit = (q > j) & valid & (borig[q] >= 0) &
                       iou_suppress(c4.x, c4.y, c4.z, c4.w, car,
                                    q4.x, q4.y, q4.z, q4.w, qar);
            unsigned bit = hit ? 1u : 0u;
            if (q < 32) cplo |= bit << q; else cphi |= bit << (q - 32);
        }
        Cplo[g][j] = cplo;
        Cphi[g][j] = cphi;
        __syncthreads();

        // ---- 3. wave 0: combine partials, exact greedy closure, append heads ----
        if (t < 64) {
            const int lane = t;
            u64 ext = 0;
            #pragma unroll
            for (int gg = 0; gg < 16; ++gg) ext |= extp[gg];
            unsigned lo = 0, hi = 0;
            #pragma unroll
            for (int gg = 0; gg < 16; ++gg) { lo |= Cplo[gg][lane]; hi |= Cphi[gg][lane]; }
            u64 C = ((u64)hi << 32) | lo;
            u64 hasC = __ballot(C != 0ull);

            u64 alive = ~ext;
            u64 selmask = 0;
            int total = count;
            while (alive && total < MAX_DET) {
                int k = __ffsll(alive) - 1;
                selmask |= (1ull << k);
                alive &= ~(1ull << k);
                ++total;
                if ((hasC >> k) & 1ull) {
                    unsigned clo = __shfl((int)(unsigned)C, k, 64);
                    unsigned chi = __shfl((int)(unsigned)(C >> 32), k, 64);
                    alive &= ~(((u64)chi << 32) | clo);
                }
            }

            if ((selmask >> lane) & 1ull) {
                int p = count + __popcll(selmask & ((1ull << lane) - 1ull));
                hbox4[p] = bbox[lane];
                harr[p]  = barr[lane];
                sel[p]   = borig[lane];
                selsc[p] = __uint_as_float((unsigned)(bkey[lane] >> 32));  // exact sigmoid bits
            }
            if (lane == 0) sh_count = total;
        }
        __syncthreads();
    }

    // ---------- Emit (wave 0; validated path) ----------
    if (t >= 64) return;
    for (int r = t; r < MAX_DET; r += 64) {
        int sidx = sel[r];
        float* o = out + (size_t)b * MAX_DET * 6 + (size_t)r * 6;
        if (sidx < 0) {
            o[0] = 0.f; o[1] = 0.f; o[2] = 0.f; o[3] = 0.f; o[4] = 0.f; o[5] = 0.f;
        } else {
            float4 bb = wb[sidx];
            int c = cls_id_b[sidx];
            o[0] = fmul(bb.x, scale);
            o[1] = fmul(bb.y, scale);
            o[2] = fmul(bb.z, scale);
            o[3] = fmul(bb.w, scale);
            o[4] = selsc[r];
            o[5] = (float)(c + 1);
        }
    }
}

extern "C" void kernel_launch(void* const* d_in, const int* in_sizes, int n_in,
                              void* d_out, int out_size, void* d_ws, size_t ws_size,
                              hipStream_t stream)
{
    const float* cls_outputs = (const float*)d_in[0];
    const float* box_outputs = (const float*)d_in[1];
    const int*   indices     = (const int*)d_in[2];
    const int*   classes     = (const int*)d_in[3];
    const float* anchors     = (const float*)d_in[4];
    const float* img_scale   = (const float*)d_in[5];
    const float* img_size    = (const float*)d_in[6];
    float*       out         = (float*)d_out;

    const int B = in_sizes[5];   // img_scale has B elements

    // workspace layout: [wmax: B*2 floats][pad to 1KB][wkeys: B*4096 u64][wboxes: B*4096 float4]
    char* wsb = (char*)d_ws;
    float*  wmax   = (float*)wsb;
    u64*    wkeys  = (u64*)(wsb + 1024);
    float4* wboxes = (float4*)(wsb + 1024 + (size_t)B * N_DET * sizeof(u64));

    dec_sort_kernel<<<dim3(B * 2), dim3(SORT_THREADS), 0, stream>>>(
        cls_outputs, box_outputs, indices, anchors, img_scale, img_size,
        wmax, wkeys, wboxes);

    scan_kernel<<<dim3(B), dim3(NTHREADS), 0, stream>>>(
        classes, img_scale, wmax, wkeys, wboxes, out);
}

// Round 12
// 37.165 us; speedup vs baseline: 1.2390x; 1.0081x over previous
//
#include <hip/hip_runtime.h>
#include <stdint.h>

#define N_DET    4096
#define HALF     2048
#define MAX_DET  100
#define NTHREADS 1024
#define SORT_THREADS 512
#define IOU_THR  0.5f

typedef unsigned long long u64;

// Explicit-rounding helpers: prevent -ffp-contract=fast from FMA-fusing and
// changing bits vs the JAX/NumPy reference (R1-R11 all passed with absmax 0.0).
__device__ __forceinline__ float fadd(float a, float b) { return __fadd_rn(a, b); }
__device__ __forceinline__ float fsub(float a, float b) { return __fsub_rn(a, b); }
__device__ __forceinline__ float fmul(float a, float b) { return __fmul_rn(a, b); }

struct Box { float x1, y1, x2, y2; };

__device__ __forceinline__ Box decode_box_v(const float4 bo, const float4 a,
                                            float sz0, float sz1)
{
    float yc_a = fmul(fadd(a.x, a.z), 0.5f);
    float xc_a = fmul(fadd(a.y, a.w), 0.5f);
    float ha = fsub(a.z, a.x);
    float wa = fsub(a.w, a.y);
    float ty = bo.x, tx = bo.y, th = bo.z, tw = bo.w;
    float we = fmul(expf(tw), wa);
    float he = fmul(expf(th), ha);
    float yc = fadd(fmul(ty, ha), yc_a);
    float xc = fadd(fmul(tx, wa), xc_a);
    Box r;
    r.x1 = fsub(xc, fmul(we, 0.5f));
    r.y1 = fsub(yc, fmul(he, 0.5f));
    r.x2 = fadd(xc, fmul(we, 0.5f));
    r.y2 = fadd(yc, fmul(he, 0.5f));
    r.x1 = fminf(fmaxf(r.x1, 0.f), sz0);
    r.y1 = fminf(fmaxf(r.y1, 0.f), sz1);
    r.x2 = fminf(fmaxf(r.x2, 0.f), sz0);
    r.y2 = fminf(fmaxf(r.y2, 0.f), sz1);
    return r;
}

__device__ __forceinline__ float sigmoidf_ref(float x)
{
    return __fdiv_rn(1.0f, __fadd_rn(1.0f, expf(-x)));
}

// head (earlier-selected) first: union = area[head] + area[cand] - inter
__device__ __forceinline__ bool iou_suppress(float hx1, float hy1, float hx2, float hy2, float har,
                                             float cx1, float cy1, float cx2, float cy2, float car)
{
    float lt0 = fmaxf(hx1, cx1);
    float lt1 = fmaxf(hy1, cy1);
    float rb0 = fminf(hx2, cx2);
    float rb1 = fminf(hy2, cy2);
    float w0 = fmaxf(fsub(rb0, lt0), 0.f);
    float w1 = fmaxf(fsub(rb1, lt1), 0.f);
    float inter = fmul(w0, w1);
    float uni = fsub(fadd(har, car), inter);
    float iou = __fdiv_rn(inter, fmaxf(uni, 1e-8f));
    return iou > IOU_THR;
}

// ---- bitonic helpers (register / shuffle) ----
__device__ __forceinline__ u64 shfl_xor_u64(u64 x, int mask)
{
    unsigned lo = (unsigned)x, hi = (unsigned)(x >> 32);
    lo = __shfl_xor(lo, mask, 64);
    hi = __shfl_xor(hi, mask, 64);
    return ((u64)hi << 32) | lo;
}

__device__ __forceinline__ void cex(u64& a, u64& b, bool desc)
{
    bool sw = desc ? (a < b) : (a > b);
    u64 ta = a, tb = b;
    a = sw ? tb : ta;
    b = sw ? ta : tb;
}

__device__ __forceinline__ void shuf_pass(u64 e[4], int d, bool desc, int l)
{
    bool lower = ((l & d) == 0);
    bool keepmax = (desc == lower);
    #pragma unroll
    for (int s = 0; s < 4; ++s) {
        u64 p = shfl_xor_u64(e[s], d);
        u64 mx = (e[s] > p) ? e[s] : p;
        u64 mn = (e[s] < p) ? e[s] : p;
        e[s] = keepmax ? mx : mn;
    }
}

// 2-slot descending merge step: element idx = 2*lane + slot, partner lane = l ^ d.
__device__ __forceinline__ void shuf_pass2(u64 e[2], int d, int l)
{
    bool keepmax = ((l & d) == 0);
    #pragma unroll
    for (int s = 0; s < 2; ++s) {
        u64 p = shfl_xor_u64(e[s], d);
        u64 mx = (e[s] > p) ? e[s] : p;
        u64 mn = (e[s] < p) ? e[s] : p;
        e[s] = keepmax ? mx : mn;
    }
}

// ============  Kernel 1: fused decode + half-sort (verbatim R11, validated)  ============
__global__ __launch_bounds__(SORT_THREADS, 1)
void dec_sort_kernel(const float* __restrict__ cls_outputs,
                     const float* __restrict__ box_outputs,
                     const int*   __restrict__ indices,
                     const float* __restrict__ anchors,
                     const float* __restrict__ img_scale,
                     const float* __restrict__ img_size,
                     float*       __restrict__ wmax,    // B * 2
                     u64*         __restrict__ wkeys,   // B * N_DET (sorted halves)
                     float4*      __restrict__ wboxes)  // B * N_DET (by orig index)
{
    __shared__ u64   keys[HALF];     // 16 KB
    __shared__ float wred[8];

    const int blk  = blockIdx.x;
    const int b    = blk >> 1;
    const int base = (blk & 1) * HALF;     // element offset within batch
    const int t    = threadIdx.x;
    const int l    = t & 63;

    const float* cls_b = cls_outputs + (size_t)b * N_DET;
    const float* box_b = box_outputs + (size_t)b * N_DET * 4;
    const int*   idx_b = indices + (size_t)b * N_DET;
    const float  scale = img_scale[b];
    const float  sz0   = __fdiv_rn(img_size[b * 2 + 0], scale);
    const float  sz1   = __fdiv_rn(img_size[b * 2 + 1], scale);

    // ---- decode 4 consecutive boxes/thread (identical arithmetic to R6-R11) ----
    u64 e[4];
    float lmax = 0.0f;
    const int4   idx4 = ((const int4*)(idx_b + base))[t];
    const float4 cl4  = ((const float4*)(cls_b + base))[t];
    const int   idxs[4] = { idx4.x, idx4.y, idx4.z, idx4.w };
    const float cls4[4] = { cl4.x, cl4.y, cl4.z, cl4.w };
    #pragma unroll
    for (int s = 0; s < 4; ++s) {
        int i = base + 4 * t + s;              // global index within batch
        float4 bo = ((const float4*)box_b)[i];          // ty,tx,th,tw
        float4 an = ((const float4*)anchors)[idxs[s]];  // a0,a1,a2,a3
        Box r = decode_box_v(bo, an, sz0, sz1);
        wboxes[(size_t)b * N_DET + i] = make_float4(r.x1, r.y1, r.x2, r.y2);
        lmax = fmaxf(lmax, fmaxf(fmaxf(r.x1, r.y1), fmaxf(r.x2, r.y2)));
        float sc = sigmoidf_ref(cls4[s]);
        e[s] = ((u64)__float_as_uint(sc) << 32) | (unsigned)(N_DET - 1 - i);
    }
    for (int o = 32; o; o >>= 1) lmax = fmaxf(lmax, __shfl_xor(lmax, o, 64));
    if (l == 0) wred[t >> 6] = lmax;

    // ---- validated half-sort (R8-R11 network) ----
    cex(e[0], e[1], true);
    cex(e[2], e[3], false);
    for (int k = 4; k <= 128; k <<= 1) {
        bool desc = (l & (k >> 2)) == 0;
        for (int j = k >> 1; j >= 4; j >>= 1) shuf_pass(e, j >> 2, desc, l);
        cex(e[0], e[2], desc); cex(e[1], e[3], desc);
        cex(e[0], e[1], desc); cex(e[2], e[3], desc);
    }
    {   // k = 256: wave-parity direction
        bool desc = ((t >> 6) & 1) == 0;
        for (int j = 128; j >= 4; j >>= 1) shuf_pass(e, j >> 2, desc, l);
        cex(e[0], e[2], desc); cex(e[1], e[3], desc);
        cex(e[0], e[1], desc); cex(e[2], e[3], desc);
    }
    #pragma unroll
    for (int s = 0; s < 4; ++s) keys[4 * t + s] = e[s];

    for (int k = 512; k <= HALF; k <<= 1) {
        for (int j = k >> 1; j >= 256; j >>= 1) {
            __syncthreads();
            #pragma unroll
            for (int vv = 0; vv < 2; ++vv) {
                int v = t + vv * SORT_THREADS;          // 0..1023 pairs
                int i   = ((v & ~(j - 1)) << 1) | (v & (j - 1));
                int ixj = i | j;
                bool desc = ((i & k) == 0);
                u64 a = keys[i], c = keys[ixj];
                bool sw = desc ? (a < c) : (a > c);
                if (sw) { keys[i] = c; keys[ixj] = a; }
            }
        }
        __syncthreads();
        u64 f[4];
        #pragma unroll
        for (int s = 0; s < 4; ++s) f[s] = keys[4 * t + s];
        bool desc = (t & (k >> 2)) == 0;               // (4t&k)==0
        for (int j = 128; j >= 4; j >>= 1) shuf_pass(f, j >> 2, desc, l);
        cex(f[0], f[2], desc); cex(f[1], f[3], desc);
        cex(f[0], f[1], desc); cex(f[2], f[3], desc);
        #pragma unroll
        for (int s = 0; s < 4; ++s) keys[4 * t + s] = f[s];
    }
    __syncthreads();
    u64* gk = wkeys + (size_t)b * N_DET + base;
    #pragma unroll
    for (int s = 0; s < 4; ++s) gk[4 * t + s] = keys[4 * t + s];

    if (t == 0) {
        float m = wred[0];
        #pragma unroll
        for (int k = 1; k < 8; ++k) m = fmaxf(m, wred[k]);
        wmax[blk] = m;   // plain store: overwritten every replay
    }
}

// ==========  Kernel 2: pre-merge + scan with overlapped publish (2 barriers/batch)  ==========
__global__ __launch_bounds__(NTHREADS, 1)
void scan_kernel(const int*    __restrict__ classes,    // B,N
                 const float*  __restrict__ img_scale,  // B
                 const float*  __restrict__ wmax,       // B * 2
                 const u64*    __restrict__ wkeys,      // sorted halves
                 const float4* __restrict__ wboxes,
                 float*        __restrict__ out)        // B,MAX_DET,6
{
    __shared__ u64    mstream[1024];   // [0:512] = exact global top-512 after pre-merge
    __shared__ float4 bbox2[2][64];    // double-buffered batch state
    __shared__ float  barr2[2][64];
    __shared__ int    borig2[2][64];
    __shared__ u64    bkey2[2][64];
    __shared__ u64    extp[16];
    __shared__ unsigned Cplo[16][64];
    __shared__ unsigned Cphi[16][64];
    __shared__ int    sel[MAX_DET];
    __shared__ float  selsc[MAX_DET];
    __shared__ float4 hbox4[MAX_DET];
    __shared__ float  harr[MAX_DET];
    __shared__ int    sh_count;
    __shared__ int    sh_pa, sh_pb, sh_pinit;   // lazy fallback merge pointers

    const int b = blockIdx.x;
    const int t = threadIdx.x;
    const int l = t & 63;

    const int*    cls_id_b = classes + (size_t)b * N_DET;
    const float   scale    = img_scale[b];
    const u64*    gA = wkeys + (size_t)b * N_DET;    // half A: orig 0..2047, desc
    const u64*    gB = gA + HALF;                    // half B: orig 2048..4095, desc
    const float4* wb = wboxes + (size_t)b * N_DET;

    const float M = fadd(fmaxf(wmax[b * 2 + 0], wmax[b * 2 + 1]), 1.0f);  // jnp.max(b)+1.0

    // ---------- Pre-merge: mstream = A[0:512] desc ++ B[0:512] asc (bitonic) ----------
    if (t < 512) mstream[t] = gA[t];
    else         mstream[t] = gB[511 - (t - 512)];
    if (t < MAX_DET) sel[t] = -1;
    if (t == 0) { sh_count = 0; sh_pinit = 0; }
    __syncthreads();

    {   // j = 512
        if (t < 512) {
            u64 a = mstream[t], c = mstream[t + 512];
            if (a < c) { mstream[t] = c; mstream[t + 512] = a; }
        }
        __syncthreads();
        // j = 256 (lower half only — upper half unused downstream)
        if (t < 256) {
            int i   = ((t & ~255) << 1) | (t & 255);
            int ixj = i | 256;
            u64 a = mstream[i], c = mstream[ixj];
            if (a < c) { mstream[i] = c; mstream[ixj] = a; }
        }
        __syncthreads();
        // j = 128..1 : blocked register phase over top 512 only (t<128)
        if (t < 128) {
            u64 f[4];
            #pragma unroll
            for (int s = 0; s < 4; ++s) f[s] = mstream[4 * t + s];
            for (int j = 128; j >= 4; j >>= 1) shuf_pass(f, j >> 2, true, l);
            cex(f[0], f[2], true); cex(f[1], f[3], true);
            cex(f[0], f[1], true); cex(f[2], f[3], true);
            #pragma unroll
            for (int s = 0; s < 4; ++s) mstream[4 * t + s] = f[s];
        }
        __syncthreads();
    }

    // ---------- Publish batch 0 into buffer 0 (fast path; c=0 < 512) ----------
    if (t < 64) {
        u64 key = mstream[t];
        int orig = N_DET - 1 - (int)(unsigned)(key & 0xFFFFFFFFull);
        bkey2[0][t] = key; borig2[0][t] = orig;
        float4 bb = wb[orig];
        float off = fmul((float)cls_id_b[orig], M);  // c.astype(f32)*(max+1)
        float x1 = fadd(bb.x, off), y1 = fadd(bb.y, off);
        float x2 = fadd(bb.z, off), y2 = fadd(bb.w, off);
        bbox2[0][t] = make_float4(x1, y1, x2, y2);
        barr2[0][t] = fmul(fmaxf(fsub(x2, x1), 0.f), fmaxf(fsub(y2, y1), 0.f));
    }
    __syncthreads();

    const int j = t & 63;
    const int g = t >> 6;
    int cur = 0;

    for (int c = 0; c < N_DET; c += 64) {
        int count = sh_count;          // uniform after barrier
        if (count >= MAX_DET) break;

        // ---- partials on buf[cur] (all 16 waves); validated R7-R11 structure ----
        float4 c4  = bbox2[cur][j];
        float  car = barr2[cur][j];
        const bool valid = (borig2[cur][j] >= 0);

        bool sup = !valid;
        for (int k = g; k < count; k += 16) {
            float4 h4 = hbox4[k];
            sup = sup | iou_suppress(h4.x, h4.y, h4.z, h4.w, harr[k],
                                     c4.x, c4.y, c4.z, c4.w, car);
        }
        u64 bal = __ballot(sup ? 1 : 0);
        if ((t & 63) == 0) extp[g] = bal;

        unsigned cplo = 0, cphi = 0;
        for (int r = g + 1; r < 64; r += 16) {
            int q = j ^ r;
            float4 q4 = bbox2[cur][q];
            float qar = barr2[cur][q];
            bool hit = (q > j) & valid & (borig2[cur][q] >= 0) &
                       iou_suppress(c4.x, c4.y, c4.z, c4.w, car,
                                    q4.x, q4.y, q4.z, q4.w, qar);
            unsigned bit = hit ? 1u : 0u;
            if (q < 32) cplo |= bit << q; else cphi |= bit << (q - 32);
        }
        Cplo[g][j] = cplo;
        Cphi[g][j] = cphi;
        __syncthreads();

        // ---- concurrent: wave 0 = closure(n); wave 1 = publish(n+1) into buf[cur^1] ----
        if (t < 64) {
            const int lane = t;
            u64 ext = 0;
            #pragma unroll
            for (int gg = 0; gg < 16; ++gg) ext |= extp[gg];
            unsigned lo = 0, hi = 0;
            #pragma unroll
            for (int gg = 0; gg < 16; ++gg) { lo |= Cplo[gg][lane]; hi |= Cphi[gg][lane]; }
            u64 C = ((u64)hi << 32) | lo;
            u64 hasC = __ballot(C != 0ull);

            u64 alive = ~ext;
            u64 selmask = 0;
            int total = count;
            while (alive && total < MAX_DET) {
                int k = __ffsll(alive) - 1;
                selmask |= (1ull << k);
                alive &= ~(1ull << k);
                ++total;
                if ((hasC >> k) & 1ull) {
                    unsigned clo = __shfl((int)(unsigned)C, k, 64);
                    unsigned chi = __shfl((int)(unsigned)(C >> 32), k, 64);
                    alive &= ~(((u64)chi << 32) | clo);
                }
            }

            if ((selmask >> lane) & 1ull) {
                int p = count + __popcll(selmask & ((1ull << lane) - 1ull));
                hbox4[p] = bbox2[cur][lane];
                harr[p]  = barr2[cur][lane];
                sel[p]   = borig2[cur][lane];
                selsc[p] = __uint_as_float((unsigned)(bkey2[cur][lane] >> 32));
            }
            if (lane == 0) sh_count = total;
        } else if (t < 128) {
            // wave 1: publish batch (c+64) into buf[cur^1]
            const int cn = c + 64;
            const int nb = cur ^ 1;
            if (cn < N_DET) {
                if (cn + 64 <= 512) {
                    // fast path from pre-merged stream
                    u64 key = mstream[cn + l];
                    int orig = N_DET - 1 - (int)(unsigned)(key & 0xFFFFFFFFull);
                    bkey2[nb][l] = key; borig2[nb][l] = orig;
                    float4 bb = wb[orig];
                    float off = fmul((float)cls_id_b[orig], M);
                    float x1 = fadd(bb.x, off), y1 = fadd(bb.y, off);
                    float x2 = fadd(bb.z, off), y2 = fadd(bb.w, off);
                    bbox2[nb][l] = make_float4(x1, y1, x2, y2);
                    barr2[nb][l] = fmul(fmaxf(fsub(x2, x1), 0.f), fmaxf(fsub(y2, y1), 0.f));
                } else {
                    // fallback: windowed 2-way merge (validated R8-R11; exact, rarely taken)
                    if (sh_pinit == 0) {
                        // lazy init of resume pointers from top-512 composition
                        int cnt = 0;
                        for (int i = l; i < 512; i += 64) {
                            int orig = N_DET - 1 - (int)(unsigned)(mstream[i] & 0xFFFFFFFFull);
                            cnt += (orig < HALF) ? 1 : 0;
                        }
                        for (int o = 32; o; o >>= 1) cnt += __shfl_xor(cnt, o, 64);
                        if (l == 0) { sh_pa = cnt; sh_pb = 512 - cnt; sh_pinit = 1; }
                    }
                    int pa = sh_pa, pb = sh_pb;   // wave-local LDS reads (same wave wrote)
                    u64 ee[2];
                    if (l < 32) {
                        int p0 = pa + 2 * l;
                        ee[0] = (p0     < HALF) ? gA[p0]     : 0ull;
                        ee[1] = (p0 + 1 < HALF) ? gA[p0 + 1] : 0ull;
                    } else {
                        int p  = 2 * (l - 32);
                        int q0 = pb + 63 - p;
                        ee[0] = (q0     < HALF) ? gB[q0]     : 0ull;
                        ee[1] = (q0 - 1 < HALF && q0 - 1 >= 0) ? gB[q0 - 1] : 0ull;
                    }
                    shuf_pass2(ee, 32, l); shuf_pass2(ee, 16, l); shuf_pass2(ee, 8, l);
                    shuf_pass2(ee, 4, l);  shuf_pass2(ee, 2, l);  shuf_pass2(ee, 1, l);
                    cex(ee[0], ee[1], true);

                    int orig0 = N_DET - 1 - (int)(unsigned)(ee[0] & 0xFFFFFFFFull);
                    int orig1 = N_DET - 1 - (int)(unsigned)(ee[1] & 0xFFFFFFFFull);
                    bool r0 = (l < 32) && (ee[0] != 0ull);
                    bool r1 = (l < 32) && (ee[1] != 0ull);
                    if (l < 32) {
                        #pragma unroll
                        for (int s = 0; s < 2; ++s) {
                            int  r    = 2 * l + s;
                            u64  key  = s ? ee[1] : ee[0];
                            int  orig = s ? orig1 : orig0;
                            bool ok   = s ? r1 : r0;
                            bkey2[nb][r] = key;
                            if (ok) {
                                float4 bb = wb[orig];
                                float off = fmul((float)cls_id_b[orig], M);
                                float x1 = fadd(bb.x, off), y1 = fadd(bb.y, off);
                                float x2 = fadd(bb.z, off), y2 = fadd(bb.w, off);
                                bbox2[nb][r] = make_float4(x1, y1, x2, y2);
                                barr2[nb][r] = fmul(fmaxf(fsub(x2, x1), 0.f),
                                                    fmaxf(fsub(y2, y1), 0.f));
                                borig2[nb][r] = orig;
                            } else {
                                bbox2[nb][r] = make_float4(0.f, 0.f, 0.f, 0.f);
                                barr2[nb][r] = 0.f;
                                borig2[nb][r] = -1;
                            }
                        }
                    }
                    u64 bR0 = __ballot(r0), bR1 = __ballot(r1);
                    u64 bA0 = __ballot(r0 && (orig0 < HALF));
                    u64 bA1 = __ballot(r1 && (orig1 < HALF));
                    int real = __popcll(bR0) + __popcll(bR1);
                    int aw   = __popcll(bA0) + __popcll(bA1);
                    if (l == 0) { sh_pa = pa + aw; sh_pb = pb + (real - aw); }
                }
            }
        }
        __syncthreads();
        cur ^= 1;
    }

    // ---------- Emit (wave 0; validated path) ----------
    if (t >= 64) return;
    for (int r = t; r < MAX_DET; r += 64) {
        int sidx = sel[r];
        float* o = out + (size_t)b * MAX_DET * 6 + (size_t)r * 6;
        if (sidx < 0) {
            o[0] = 0.f; o[1] = 0.f; o[2] = 0.f; o[3] = 0.f; o[4] = 0.f; o[5] = 0.f;
        } else {
            float4 bb = wb[sidx];
            int c = cls_id_b[sidx];
            o[0] = fmul(bb.x, scale);
            o[1] = fmul(bb.y, scale);
            o[2] = fmul(bb.z, scale);
            o[3] = fmul(bb.w, scale);
            o[4] = selsc[r];
            o[5] = (float)(c + 1);
        }
    }
}

extern "C" void kernel_launch(void* const* d_in, const int* in_sizes, int n_in,
                              void* d_out, int out_size, void* d_ws, size_t ws_size,
                              hipStream_t stream)
{
    const float* cls_outputs = (const float*)d_in[0];
    const float* box_outputs = (const float*)d_in[1];
    const int*   indices     = (const int*)d_in[2];
    const int*   classes     = (const int*)d_in[3];
    const float* anchors     = (const float*)d_in[4];
    const float* img_scale   = (const float*)d_in[5];
    const float* img_size    = (const float*)d_in[6];
    float*       out         = (float*)d_out;

    const int B = in_sizes[5];   // img_scale has B elements

    // workspace layout: [wmax: B*2 floats][pad to 1KB][wkeys: B*4096 u64][wboxes: B*4096 float4]
    char* wsb = (char*)d_ws;
    float*  wmax   = (float*)wsb;
    u64*    wkeys  = (u64*)(wsb + 1024);
    float4* wboxes = (float4*)(wsb + 1024 + (size_t)B * N_DET * sizeof(u64));

    dec_sort_kernel<<<dim3(B * 2), dim3(SORT_THREADS), 0, stream>>>(
        cls_outputs, box_outputs, indices, anchors, img_scale, img_size,
        wmax, wkeys, wboxes);

    scan_kernel<<<dim3(B), dim3(NTHREADS), 0, stream>>>(
        classes, img_scale, wmax, wkeys, wboxes, out);
}